// Round 8
// baseline (391.527 us; speedup 1.0000x reference)
//
#include <hip/hip_runtime.h>
#include <hip/hip_bf16.h>

#define B_ 256
#define D_ 2048
#define N_ 30000
#define INV_TEMP 20.0f
#define MOM 0.2f
#define EPSF 1e-12f
#define BN 48
#define KC 64
#define NT 625   // 30000 / 48
#define NK 32    // D_ / KC
#define NBL 40   // kloss1 blocks
#define TPB 16   // tiles per kloss1 block

typedef __attribute__((ext_vector_type(8))) short bf16x8;
typedef __attribute__((ext_vector_type(4))) float f32x4;

__device__ __forceinline__ unsigned short f2bf(float f) {
  union { float f; unsigned int u; } v; v.f = f;
  unsigned int u = v.u;
  unsigned int r = (u + 0x7fffu + ((u >> 16) & 1u)) >> 16;
  return (unsigned short)r;
}

__device__ __forceinline__ float blockReduceSum256(float v) {
  __shared__ float red[4];
  #pragma unroll
  for (int m = 32; m >= 1; m >>= 1) v += __shfl_xor(v, m, 64);
  int lane = threadIdx.x & 63, w = threadIdx.x >> 6;
  __syncthreads();
  if (lane == 0) red[w] = v;
  __syncthreads();
  return red[0] + red[1] + red[2] + red[3];
}

// ---------------- Kernel A: normalize inputs, emit fp32 + bf16 copies -------
__global__ __launch_bounds__(256) void knorm(const float* __restrict__ in,
                                             float* __restrict__ x,
                                             unsigned short* __restrict__ xbf) {
  int b = blockIdx.x, t = threadIdx.x;
  const float* row = in + (size_t)b * D_;
  float vals[8]; float ss = 0.f;
  #pragma unroll
  for (int i = 0; i < 8; i++) { float f = row[t + i * 256]; vals[i] = f; ss += f * f; }
  float tot = blockReduceSum256(ss);
  float inv = 1.0f / (sqrtf(tot) + EPSF);
  #pragma unroll
  for (int i = 0; i < 8; i++) {
    float xv = vals[i] * inv;
    x[(size_t)b * D_ + t + i * 256] = xv;
    xbf[(size_t)b * D_ + t + i * 256] = f2bf(xv);
  }
}

// ---------------- Kernel B: 1-barrier/step pipeline + line-aligned copy -----
// BM=256, BN=48, 4 waves (wave owns 64 rows). Regs hold tile t+1; LDS dbuf;
// per-step fence is lgkm-only (global loads/stores ride across barriers).
// outF copy: aligned float4 {prev,x,y,z} via lane-1 shuffle + c15 carry.
__global__ __launch_bounds__(256, 2) void kmain(const float* __restrict__ feats,
                                                const unsigned short* __restrict__ xbf,
                                                float* __restrict__ outp,
                                                float* __restrict__ pmax,
                                                float* __restrict__ psum) {
  __shared__ __align__(16) unsigned short xs[2][16384];  // 2 x 256rows x 64cols bf16
  __shared__ __align__(16) unsigned short fs[2][3072];   // 2 x 48rows x 64cols bf16
  int tid = threadIdx.x, wave = tid >> 6, lane = tid & 63;
  int n0 = blockIdx.x * BN;
  int q = lane >> 4, lr = lane & 15;
  int slp = (lane & 48) | ((lane - 1) & 15);  // lane-1 within 16-group (c-1)
  int slc = (lane & 48) | 15;                 // c15 of this 16-group

  // xs map: fi = tid + i*256 (i<8) -> row b=fi>>3 in [0,256), 16B chunk g=fi&7
  // fs map: fi = tid + i*256 (i<3) -> row n=fi>>4 in [0,48), float4 chunk c=fi&15
  int fn[3], fc[3];
  #pragma unroll
  for (int i = 0; i < 3; i++) { int fi = tid + i * 256; fn[i] = fi >> 4; fc[i] = fi & 15; }

  uint4  xv[8];
  float4 fv[3];
  float  carry[3] = {0.f, 0.f, 0.f};

  // prologue: load tile 0 into regs
  #pragma unroll
  for (int i = 0; i < 3; i++)
    fv[i] = *(const float4*)(feats + (size_t)(n0 + fn[i]) * D_ + 4 * fc[i]);
  #pragma unroll
  for (int i = 0; i < 8; i++) {
    int fi = tid + i * 256, b = fi >> 3, g = fi & 7;
    xv[i] = *(const uint4*)(xbf + (size_t)b * D_ + g * 8);
  }

  f32x4 acc[4][3];
  #pragma unroll
  for (int i = 0; i < 4; i++)
    #pragma unroll
    for (int j = 0; j < 3; j++) acc[i][j] = f32x4{0.f, 0.f, 0.f, 0.f};

  for (int t = 0; t < NK; t++) {
    int cur = t & 1;
    unsigned short* xc  = &xs[cur][0];
    unsigned short* fcb = &fs[cur][0];
    // --- phase A: ds_write tile t + line-aligned copy-out + carry update ---
    #pragma unroll
    for (int i = 0; i < 8; i++) {
      int fi = tid + i * 256, b = fi >> 3, g = fi & 7;
      int byte = b * 128 + ((g * 16) ^ ((b & 7) << 4));
      *(uint4*)((char*)xc + byte) = xv[i];
    }
    #pragma unroll
    for (int i = 0; i < 3; i++) {
      float4 v = fv[i];
      union { __hip_bfloat162 h2[2]; uint2 u8; } pk;
      pk.h2[0] = __float22bfloat162_rn(make_float2(v.x, v.y));
      pk.h2[1] = __float22bfloat162_rn(make_float2(v.z, v.w));
      int byte = fn[i] * 128 + ((8 * fc[i]) ^ ((fn[i] & 7) << 4));
      *(uint2*)((char*)fcb + byte) = pk.u8;
      // copy-out: out[rb] = feats[rb-1] (prev elem), then v.x..v.z
      float pw_p = __shfl(v.w, slp, 64);        // (c-1)'s v.w, same step
      float pw_c = __shfl(carry[i], slc, 64);   // c15's carry, prev chunk last
      float prev = (fc[i] == 0) ? pw_c : pw_p;
      size_t rb = (size_t)(n0 + fn[i]) * D_ + t * KC + 4 * fc[i];  // out-absolute
      if (t == 0 && fc[i] == 0) {
        outp[rb + 1] = v.x; outp[rb + 2] = v.y; outp[rb + 3] = v.z;
      } else {
        *(float4*)(outp + rb) = make_float4(prev, v.x, v.y, v.z);
      }
      carry[i] = v.w;
    }
    // --- phase B: issue loads for tile t+1 (ride across the barrier) ---
    if (t + 1 < NK) {
      int kl = (t + 1) * KC;
      #pragma unroll
      for (int i = 0; i < 3; i++)
        fv[i] = *(const float4*)(feats + (size_t)(n0 + fn[i]) * D_ + kl + 4 * fc[i]);
      #pragma unroll
      for (int i = 0; i < 8; i++) {
        int fi = tid + i * 256, b = fi >> 3, g = fi & 7;
        xv[i] = *(const uint4*)(xbf + (size_t)b * D_ + kl + g * 8);
      }
    }
    // --- phase C: lgkm-only fence + barrier (NO vmcnt drain) ---
    __builtin_amdgcn_sched_barrier(0);
    asm volatile("s_waitcnt lgkmcnt(0)" ::: "memory");
    __builtin_amdgcn_s_barrier();
    __builtin_amdgcn_sched_barrier(0);
    // --- phase D: compute tile t ---
    #pragma unroll
    for (int ks = 0; ks < 2; ks++) {
      int g = ks * 4 + q;
      bf16x8 a[4], bb[3];
      #pragma unroll
      for (int mi = 0; mi < 4; mi++) {
        int row = wave * 64 + mi * 16 + lr;
        a[mi] = *(const bf16x8*)((char*)xc + row * 128 + ((g * 16) ^ ((row & 7) << 4)));
      }
      #pragma unroll
      for (int ni = 0; ni < 3; ni++) {
        int row = ni * 16 + lr;
        bb[ni] = *(const bf16x8*)((char*)fcb + row * 128 + ((g * 16) ^ ((row & 7) << 4)));
      }
      #pragma unroll
      for (int mi = 0; mi < 4; mi++)
        #pragma unroll
        for (int ni = 0; ni < 3; ni++)
          acc[mi][ni] = __builtin_amdgcn_mfma_f32_16x16x32_bf16(a[mi], bb[ni], acc[mi][ni], 0, 0, 0);
    }
  }

  // row-final element: out[(r+1)*2048] = feats[r][2047] (c15 carry)
  #pragma unroll
  for (int i = 0; i < 3; i++)
    if (fc[i] == 15)
      outp[(size_t)(n0 + fn[i]) * D_ + D_] = carry[i];

  // ---- epilogue: per-row partial max/sumexp over this block's 48 cols ----
  #pragma unroll
  for (int mi = 0; mi < 4; mi++) {
    #pragma unroll
    for (int r = 0; r < 4; r++) {
      float v0 = acc[mi][0][r] * INV_TEMP;
      float v1 = acc[mi][1][r] * INV_TEMP;
      float v2 = acc[mi][2][r] * INV_TEMP;
      float mx = fmaxf(fmaxf(v0, v1), v2);
      #pragma unroll
      for (int m = 8; m >= 1; m >>= 1) mx = fmaxf(mx, __shfl_xor(mx, m, 64));
      float s = __expf(v0 - mx) + __expf(v1 - mx) + __expf(v2 - mx);
      #pragma unroll
      for (int m = 8; m >= 1; m >>= 1) s += __shfl_xor(s, m, 64);
      if (lr == 0) {
        int row = wave * 64 + mi * 16 + q * 4 + r;
        pmax[(size_t)blockIdx.x * 256 + row] = mx;
        psum[(size_t)blockIdx.x * 256 + row] = s;
      }
    }
  }
}

// ---------------- Kernel C: exact fp32 target logits ------------------------
__global__ __launch_bounds__(256) void ktdot(const float* __restrict__ feats,
                                             const float* __restrict__ x,
                                             const int* __restrict__ tgt,
                                             float* __restrict__ tdot) {
  int b = blockIdx.x, t = threadIdx.x;
  int y = tgt[b];
  const float* fr = feats + (size_t)y * D_;
  const float* xr = x + (size_t)b * D_;
  float s = 0.f;
  #pragma unroll
  for (int i = 0; i < 8; i++) s += fr[t + i * 256] * xr[t + i * 256];
  float tot = blockReduceSum256(s);
  if (t == 0) tdot[b] = tot * INV_TEMP;
}

// ---------------- Kernel D1: coalesced tile-range combine (40 blocks) -------
__global__ __launch_bounds__(256) void kloss1(const float* __restrict__ pmax,
                                              const float* __restrict__ psum,
                                              float* __restrict__ pm2,
                                              float* __restrict__ ps2) {
  int b = threadIdx.x, j = blockIdx.x;
  float m = -INFINITY, s = 0.f;
  #pragma unroll 4
  for (int i = 0; i < TPB; i++) {
    int tile = j * TPB + i;
    if (tile >= NT) break;
    float mt = pmax[(size_t)tile * 256 + b];
    float st = psum[(size_t)tile * 256 + b];
    if (mt > m) { s = s * __expf(m - mt) + st; m = mt; }
    else        { s += st * __expf(mt - m); }
  }
  pm2[j * 256 + b] = m;
  ps2[j * 256 + b] = s;
}

// ---------------- Kernel D2: final combine + mean -> loss -------------------
__global__ __launch_bounds__(256) void kloss2(const float* __restrict__ pm2,
                                              const float* __restrict__ ps2,
                                              const float* __restrict__ tdot,
                                              float* __restrict__ out) {
  int b = threadIdx.x;
  float m = -INFINITY, s = 0.f;
  for (int j = 0; j < NBL; j++) {
    float mt = pm2[j * 256 + b];
    float st = ps2[j * 256 + b];
    float M = fmaxf(m, mt);
    s = s * __expf(m - M) + st * __expf(mt - M);
    m = M;
  }
  float lb = m + logf(s) - tdot[b];
  float tot = blockReduceSum256(lb);
  if (b == 0) out[0] = tot * (1.0f / 256.0f);
}

// ---------------- Kernel E: momentum update (first-occurrence chains) -------
__global__ __launch_bounds__(256) void kupdate(const float* __restrict__ feats,
                                               const float* __restrict__ x,
                                               const int* __restrict__ tgt,
                                               float* __restrict__ outF) {
  int b = blockIdx.x, t = threadIdx.x;
  int y = tgt[b];
  for (int i = 0; i < b; i++) if (tgt[i] == y) return;  // block-uniform exit
  float f[8];
  #pragma unroll
  for (int i = 0; i < 8; i++) f[i] = feats[(size_t)y * D_ + t + i * 256];
  for (int b2 = b; b2 < B_; b2++) {
    if (tgt[b2] != y) continue;  // block-uniform
    float ss = 0.f;
    #pragma unroll
    for (int i = 0; i < 8; i++) {
      f[i] = MOM * f[i] + (1.0f - MOM) * x[(size_t)b2 * D_ + t + i * 256];
      ss += f[i] * f[i];
    }
    float tot = blockReduceSum256(ss);
    float inv = 1.0f / (sqrtf(tot) + EPSF);
    #pragma unroll
    for (int i = 0; i < 8; i++) f[i] *= inv;
  }
  #pragma unroll
  for (int i = 0; i < 8; i++) outF[(size_t)y * D_ + t + i * 256] = f[i];
}

extern "C" void kernel_launch(void* const* d_in, const int* in_sizes, int n_in,
                              void* d_out, int out_size, void* d_ws, size_t ws_size,
                              hipStream_t stream) {
  const float* inputs = (const float*)d_in[0];
  const float* feats  = (const float*)d_in[1];
  const int*   tgt    = (const int*)d_in[2];
  float* out  = (float*)d_out;
  float* outF = out + 1;  // new_features, N_ x D_

  char* ws = (char*)d_ws;
  float*          x    = (float*)ws;                                   // 2 MB
  unsigned short* xbf  = (unsigned short*)(ws + (size_t)B_ * D_ * 4);  // 1 MB
  float*          pmax = (float*)(ws + (size_t)B_ * D_ * 4 + (size_t)B_ * D_ * 2);
  float*          psum = pmax + (size_t)NT * 256;
  float*          pm2  = psum + (size_t)NT * 256;
  float*          ps2  = pm2 + (size_t)NBL * 256;
  float*          tdot = ps2 + (size_t)NBL * 256;

  hipLaunchKernelGGL(knorm,   dim3(B_),  dim3(256), 0, stream, inputs, x, xbf);
  hipLaunchKernelGGL(kmain,   dim3(NT),  dim3(256), 0, stream, feats, xbf, out, pmax, psum);
  hipLaunchKernelGGL(ktdot,   dim3(B_),  dim3(256), 0, stream, feats, x, tgt, tdot);
  hipLaunchKernelGGL(kloss1,  dim3(NBL), dim3(256), 0, stream, pmax, psum, pm2, ps2);
  hipLaunchKernelGGL(kloss2,  dim3(1),   dim3(256), 0, stream, pm2, ps2, tdot, out);
  hipLaunchKernelGGL(kupdate, dim3(B_),  dim3(256), 0, stream, feats, x, tgt, outF);
}

// Round 9
// 222.111 us; speedup vs baseline: 1.7628x; 1.7628x over previous
//
#include <hip/hip_runtime.h>
#include <hip/hip_bf16.h>

#define B_ 256
#define D_ 2048
#define N_ 30000
#define INV_TEMP 20.0f
#define MOM 0.2f
#define EPSF 1e-12f
#define BN 48
#define KC 64
#define KH 1024  // K half size
#define NKH 16   // K-steps per block (KH/KC)
#define NT 625   // 30000 / 48
#define NBL 40   // kloss1 blocks
#define TPB 16   // tiles per kloss1 block

typedef __attribute__((ext_vector_type(8))) short bf16x8;
typedef __attribute__((ext_vector_type(4))) float f32x4;

typedef const __attribute__((address_space(1))) void* gas_t;
typedef __attribute__((address_space(3))) void* las_t;
#define GLOAD16(g, l) __builtin_amdgcn_global_load_lds((gas_t)(g), (las_t)(l), 16, 0, 0)

__device__ __forceinline__ unsigned short f2bf(float f) {
  union { float f; unsigned int u; } v; v.f = f;
  unsigned int u = v.u;
  unsigned int r = (u + 0x7fffu + ((u >> 16) & 1u)) >> 16;
  return (unsigned short)r;
}

__device__ __forceinline__ float blockReduceSum256(float v) {
  __shared__ float red[4];
  #pragma unroll
  for (int m = 32; m >= 1; m >>= 1) v += __shfl_xor(v, m, 64);
  int lane = threadIdx.x & 63, w = threadIdx.x >> 6;
  __syncthreads();
  if (lane == 0) red[w] = v;
  __syncthreads();
  return red[0] + red[1] + red[2] + red[3];
}

// ---------------- Kernel A: normalize inputs, emit fp32 + bf16 copies -------
__global__ __launch_bounds__(256) void knorm(const float* __restrict__ in,
                                             float* __restrict__ x,
                                             unsigned short* __restrict__ xbf) {
  int b = blockIdx.x, t = threadIdx.x;
  const float* row = in + (size_t)b * D_;
  float vals[8]; float ss = 0.f;
  #pragma unroll
  for (int i = 0; i < 8; i++) { float f = row[t + i * 256]; vals[i] = f; ss += f * f; }
  float tot = blockReduceSum256(ss);
  float inv = 1.0f / (sqrtf(tot) + EPSF);
  #pragma unroll
  for (int i = 0; i < 8; i++) {
    float xv = vals[i] * inv;
    x[(size_t)b * D_ + t + i * 256] = xv;
    xbf[(size_t)b * D_ + t + i * 256] = f2bf(xv);
  }
}

// ---------------- Kernel B: K-split GEMM (r2 serial skeleton) + fused copy --
// Block (nb, kh): BN=48 cols x K-half kh. 16 steps, drain every step (clean
// write-combining), 38 KB LDS -> 4 blocks/CU resident -> 4 independent
// latency chains per CU. Raw partial dots -> pacc slab; kacc combines.
__global__ __launch_bounds__(256, 4) void kmain(const float* __restrict__ feats,
                                                const unsigned short* __restrict__ xbf,
                                                float* __restrict__ outp,   // = out (raw base)
                                                float* __restrict__ pacc) {
  __shared__ __align__(16) unsigned short xs[16384];  // 256 rows x 64 cols bf16
  __shared__ __align__(16) unsigned short fs[3072];   // 48 rows x 64 cols bf16
  int tid = threadIdx.x, wave = tid >> 6, lane = tid & 63;
  int nb = blockIdx.x >> 1, kh = blockIdx.x & 1;
  int n0 = nb * BN, kbase = kh * KH;
  int q = lane >> 4, lr = lane & 15;
  int slp = (lane & 48) | ((lane - 1) & 15);  // (c-1) lane within 16-group
  int slc = (lane & 48) | 15;                 // c15 lane of this 16-group

  // xs gl_lds map: iter i stages rows i*32 + wave*8 + (l>>3), chunk l&7
  int gswz = (lane & 7) ^ (lane >> 3);
  int rof = wave * 8 + (lane >> 3);
  const char* xsrc = (const char*)xbf;

  // fs map: fi = tid + i*256 -> row n=fi>>4 in [0,48), float4 chunk c=fi&15
  int fn[3], fc[3];
  #pragma unroll
  for (int i = 0; i < 3; i++) { int fi = tid + i * 256; fn[i] = fi >> 4; fc[i] = fi & 15; }
  float carry[3] = {0.f, 0.f, 0.f};

  f32x4 acc[4][3];
  #pragma unroll
  for (int i = 0; i < 4; i++)
    #pragma unroll
    for (int j = 0; j < 3; j++) acc[i][j] = f32x4{0.f, 0.f, 0.f, 0.f};

  for (int t = 0; t < NKH; t++) {
    int k0 = kbase + t * KC;
    __syncthreads();   // xs/fs reusable
    // ---- stage ----
    float4 fv[3];
    #pragma unroll
    for (int i = 0; i < 3; i++)
      fv[i] = *(const float4*)(feats + (size_t)(n0 + fn[i]) * D_ + k0 + 4 * fc[i]);
    size_t gb = ((size_t)rof * D_ + k0 + gswz * 8) * 2;
    #pragma unroll
    for (int i = 0; i < 8; i++)
      GLOAD16(xsrc + gb + (size_t)i * 32 * D_ * 2,
              (char*)xs + i * 4096 + wave * 1024);
    #pragma unroll
    for (int i = 0; i < 3; i++) {
      float4 v = fv[i];
      union { __hip_bfloat162 h2[2]; uint2 u8; } pk;
      pk.h2[0] = __float22bfloat162_rn(make_float2(v.x, v.y));
      pk.h2[1] = __float22bfloat162_rn(make_float2(v.z, v.w));
      int byte = fn[i] * 128 + ((8 * fc[i]) ^ ((fn[i] & 7) << 4));
      *(uint2*)((char*)fs + byte) = pk.u8;
      // fused copy: out[rb] holds element rb-1 (out = loss + flattened feats)
      float pw_p = __shfl(v.w, slp, 64);        // (c-1)'s v.w, same step
      float pw_c = __shfl(carry[i], slc, 64);   // c15's carry, prev step last
      float prev = (fc[i] == 0) ? pw_c : pw_p;
      size_t rb = (size_t)(n0 + fn[i]) * D_ + k0 + 4 * fc[i];
      if (t == 0 && fc[i] == 0) {
        outp[rb + 1] = v.x; outp[rb + 2] = v.y; outp[rb + 3] = v.z;
      } else {
        *(float4*)(outp + rb) = make_float4(prev, v.x, v.y, v.z);
      }
      carry[i] = v.w;
    }
    __syncthreads();   // drain: gl_lds landed, fs visible, stores acked
    // ---- compute ----
    #pragma unroll
    for (int ks = 0; ks < 2; ks++) {
      int g = ks * 4 + q;
      bf16x8 a[4], bb[3];
      #pragma unroll
      for (int mi = 0; mi < 4; mi++) {
        int row = wave * 64 + mi * 16 + lr;
        a[mi] = *(const bf16x8*)((char*)xs + row * 128 + ((g * 16) ^ ((row & 7) << 4)));
      }
      #pragma unroll
      for (int ni = 0; ni < 3; ni++) {
        int row = ni * 16 + lr;
        bb[ni] = *(const bf16x8*)((char*)fs + row * 128 + ((g * 16) ^ ((row & 7) << 4)));
      }
      #pragma unroll
      for (int mi = 0; mi < 4; mi++)
        #pragma unroll
        for (int ni = 0; ni < 3; ni++)
          acc[mi][ni] = __builtin_amdgcn_mfma_f32_16x16x32_bf16(a[mi], bb[ni], acc[mi][ni], 0, 0, 0);
    }
  }

  // half-boundary element: out[row*D_ + kbase + KH] = element (row, kbase+1023)
  #pragma unroll
  for (int i = 0; i < 3; i++)
    if (fc[i] == 15)
      outp[(size_t)(n0 + fn[i]) * D_ + kbase + KH] = carry[i];

  // raw partial dots -> pacc[blockIdx][row][col], dense 256x48
  float* pb = pacc + (size_t)blockIdx.x * (256 * 48);
  #pragma unroll
  for (int mi = 0; mi < 4; mi++)
    #pragma unroll
    for (int r = 0; r < 4; r++) {
      int row = wave * 64 + mi * 16 + q * 4 + r;
      #pragma unroll
      for (int ni = 0; ni < 3; ni++)
        pb[row * 48 + ni * 16 + lr] = acc[mi][ni][r];
    }
}

// ---------------- Kernel B2: combine K-halves -> per-tile max/sumexp --------
__global__ __launch_bounds__(256) void kacc(const float* __restrict__ pacc,
                                            float* __restrict__ pmax,
                                            float* __restrict__ psum) {
  int nb = blockIdx.x, b = threadIdx.x;
  const float* p0 = pacc + ((size_t)2 * nb) * (256 * 48) + b * 48;
  const float* p1 = p0 + 256 * 48;
  float v[48];
  float mx = -INFINITY;
  #pragma unroll
  for (int c = 0; c < 48; c += 4) {
    float4 a = *(const float4*)(p0 + c);
    float4 d = *(const float4*)(p1 + c);
    v[c + 0] = (a.x + d.x) * INV_TEMP;
    v[c + 1] = (a.y + d.y) * INV_TEMP;
    v[c + 2] = (a.z + d.z) * INV_TEMP;
    v[c + 3] = (a.w + d.w) * INV_TEMP;
    mx = fmaxf(mx, fmaxf(fmaxf(v[c], v[c + 1]), fmaxf(v[c + 2], v[c + 3])));
  }
  float s = 0.f;
  #pragma unroll
  for (int c = 0; c < 48; c++) s += __expf(v[c] - mx);
  pmax[(size_t)nb * 256 + b] = mx;
  psum[(size_t)nb * 256 + b] = s;
}

// ---------------- Kernel C: exact fp32 target logits ------------------------
__global__ __launch_bounds__(256) void ktdot(const float* __restrict__ feats,
                                             const float* __restrict__ x,
                                             const int* __restrict__ tgt,
                                             float* __restrict__ tdot) {
  int b = blockIdx.x, t = threadIdx.x;
  int y = tgt[b];
  const float* fr = feats + (size_t)y * D_;
  const float* xr = x + (size_t)b * D_;
  float s = 0.f;
  #pragma unroll
  for (int i = 0; i < 8; i++) s += fr[t + i * 256] * xr[t + i * 256];
  float tot = blockReduceSum256(s);
  if (t == 0) tdot[b] = tot * INV_TEMP;
}

// ---------------- Kernel D1: coalesced tile-range combine (40 blocks) -------
__global__ __launch_bounds__(256) void kloss1(const float* __restrict__ pmax,
                                              const float* __restrict__ psum,
                                              float* __restrict__ pm2,
                                              float* __restrict__ ps2) {
  int b = threadIdx.x, j = blockIdx.x;
  float m = -INFINITY, s = 0.f;
  #pragma unroll 4
  for (int i = 0; i < TPB; i++) {
    int tile = j * TPB + i;
    if (tile >= NT) break;
    float mt = pmax[(size_t)tile * 256 + b];
    float st = psum[(size_t)tile * 256 + b];
    if (mt > m) { s = s * __expf(m - mt) + st; m = mt; }
    else        { s += st * __expf(mt - m); }
  }
  pm2[j * 256 + b] = m;
  ps2[j * 256 + b] = s;
}

// ---------------- Kernel D2: final combine + mean -> loss -------------------
__global__ __launch_bounds__(256) void kloss2(const float* __restrict__ pm2,
                                              const float* __restrict__ ps2,
                                              const float* __restrict__ tdot,
                                              float* __restrict__ out) {
  int b = threadIdx.x;
  float m = -INFINITY, s = 0.f;
  for (int j = 0; j < NBL; j++) {
    float mt = pm2[j * 256 + b];
    float st = ps2[j * 256 + b];
    float M = fmaxf(m, mt);
    s = s * __expf(m - M) + st * __expf(mt - M);
    m = M;
  }
  float lb = m + logf(s) - tdot[b];
  float tot = blockReduceSum256(lb);
  if (b == 0) out[0] = tot * (1.0f / 256.0f);
}

// ---------------- Kernel E: momentum update (first-occurrence chains) -------
__global__ __launch_bounds__(256) void kupdate(const float* __restrict__ feats,
                                               const float* __restrict__ x,
                                               const int* __restrict__ tgt,
                                               float* __restrict__ outF) {
  int b = blockIdx.x, t = threadIdx.x;
  int y = tgt[b];
  for (int i = 0; i < b; i++) if (tgt[i] == y) return;  // block-uniform exit
  float f[8];
  #pragma unroll
  for (int i = 0; i < 8; i++) f[i] = feats[(size_t)y * D_ + t + i * 256];
  for (int b2 = b; b2 < B_; b2++) {
    if (tgt[b2] != y) continue;  // block-uniform
    float ss = 0.f;
    #pragma unroll
    for (int i = 0; i < 8; i++) {
      f[i] = MOM * f[i] + (1.0f - MOM) * x[(size_t)b2 * D_ + t + i * 256];
      ss += f[i] * f[i];
    }
    float tot = blockReduceSum256(ss);
    float inv = 1.0f / (sqrtf(tot) + EPSF);
    #pragma unroll
    for (int i = 0; i < 8; i++) f[i] *= inv;
  }
  #pragma unroll
  for (int i = 0; i < 8; i++) outF[(size_t)y * D_ + t + i * 256] = f[i];
}

extern "C" void kernel_launch(void* const* d_in, const int* in_sizes, int n_in,
                              void* d_out, int out_size, void* d_ws, size_t ws_size,
                              hipStream_t stream) {
  const float* inputs = (const float*)d_in[0];
  const float* feats  = (const float*)d_in[1];
  const int*   tgt    = (const int*)d_in[2];
  float* out  = (float*)d_out;
  float* outF = out + 1;  // new_features, N_ x D_

  char* ws = (char*)d_ws;
  // pacc first (largest, 16B-aligned): 1250 * 256 * 48 * 4 = 61,440,000 B
  float*          pacc = (float*)ws;
  size_t off = (size_t)1250 * 256 * 48 * 4;
  float*          x    = (float*)(ws + off);            off += (size_t)B_ * D_ * 4;
  unsigned short* xbf  = (unsigned short*)(ws + off);   off += (size_t)B_ * D_ * 2;
  float*          pmax = (float*)(ws + off);            off += (size_t)NT * 256 * 4;
  float*          psum = (float*)(ws + off);            off += (size_t)NT * 256 * 4;
  float*          pm2  = (float*)(ws + off);            off += (size_t)NBL * 256 * 4;
  float*          ps2  = (float*)(ws + off);            off += (size_t)NBL * 256 * 4;
  float*          tdot = (float*)(ws + off);

  hipLaunchKernelGGL(knorm,   dim3(B_),    dim3(256), 0, stream, inputs, x, xbf);
  hipLaunchKernelGGL(kmain,   dim3(1250),  dim3(256), 0, stream, feats, xbf, out, pacc);
  hipLaunchKernelGGL(kacc,    dim3(NT),    dim3(256), 0, stream, pacc, pmax, psum);
  hipLaunchKernelGGL(ktdot,   dim3(B_),    dim3(256), 0, stream, feats, x, tgt, tdot);
  hipLaunchKernelGGL(kloss1,  dim3(NBL),   dim3(256), 0, stream, pmax, psum, pm2, ps2);
  hipLaunchKernelGGL(kloss2,  dim3(1),     dim3(256), 0, stream, pm2, ps2, tdot, out);
  hipLaunchKernelGGL(kupdate, dim3(B_),    dim3(256), 0, stream, feats, x, tgt, outF);
}

// Round 10
// 216.922 us; speedup vs baseline: 1.8049x; 1.0239x over previous
//
#include <hip/hip_runtime.h>
#include <hip/hip_bf16.h>

#define B_ 256
#define D_ 2048
#define N_ 30000
#define INV_TEMP 20.0f
#define MOM 0.2f
#define EPSF 1e-12f
#define BM 128
#define BN 48
#define KC 64
#define NT 625   // 30000 / 48
#define NK 32    // D_ / KC
#define NBL 40   // kloss1 blocks
#define TPB 16   // tiles per kloss1 block

typedef __attribute__((ext_vector_type(8))) short bf16x8;
typedef __attribute__((ext_vector_type(4))) float f32x4;

typedef const __attribute__((address_space(1))) void* gas_t;
typedef __attribute__((address_space(3))) void* las_t;
#define GLOAD16(g, l) __builtin_amdgcn_global_load_lds((gas_t)(g), (las_t)(l), 16, 0, 0)

__device__ __forceinline__ unsigned short f2bf(float f) {
  union { float f; unsigned int u; } v; v.f = f;
  unsigned int u = v.u;
  unsigned int r = (u + 0x7fffu + ((u >> 16) & 1u)) >> 16;
  return (unsigned short)r;
}

__device__ __forceinline__ float blockReduceSum256(float v) {
  __shared__ float red[4];
  #pragma unroll
  for (int m = 32; m >= 1; m >>= 1) v += __shfl_xor(v, m, 64);
  int lane = threadIdx.x & 63, w = threadIdx.x >> 6;
  __syncthreads();
  if (lane == 0) red[w] = v;
  __syncthreads();
  return red[0] + red[1] + red[2] + red[3];
}

// ---------------- Kernel A: normalize inputs, emit fp32 + bf16 copies -------
__global__ __launch_bounds__(256) void knorm(const float* __restrict__ in,
                                             float* __restrict__ x,
                                             unsigned short* __restrict__ xbf) {
  int b = blockIdx.x, t = threadIdx.x;
  const float* row = in + (size_t)b * D_;
  float vals[8]; float ss = 0.f;
  #pragma unroll
  for (int i = 0; i < 8; i++) { float f = row[t + i * 256]; vals[i] = f; ss += f * f; }
  float tot = blockReduceSum256(ss);
  float inv = 1.0f / (sqrtf(tot) + EPSF);
  #pragma unroll
  for (int i = 0; i < 8; i++) {
    float xv = vals[i] * inv;
    x[(size_t)b * D_ + t + i * 256] = xv;
    xbf[(size_t)b * D_ + t + i * 256] = f2bf(xv);
  }
}

// ---------------- Kernel B: PURE GEMM, BM=128 x BN=48, serial skeleton ------
// Block (nb, mb): batch rows [mb*128, +128), feature cols [nb*48, +48).
// No global stores in the K-loop -> the per-step vmcnt(0) drain waits only
// on loads. 22 KB LDS -> ~6 blocks/CU; all 1250 blocks resident at once.
__global__ __launch_bounds__(256, 6) void kmain(const float* __restrict__ feats,
                                                const unsigned short* __restrict__ xbf,
                                                float* __restrict__ pmax,
                                                float* __restrict__ psum) {
  __shared__ __align__(16) unsigned short xs[8192];   // 128 rows x 64 cols bf16, 16 KB
  __shared__ __align__(16) unsigned short fs[3072];   // 48 rows x 64 cols bf16, 6 KB
  int tid = threadIdx.x, wave = tid >> 6, lane = tid & 63;
  int nb = blockIdx.x >> 1, mb = blockIdx.x & 1;
  int n0 = nb * BN;
  int q = lane >> 4, lr = lane & 15;

  // xs gl_lds map: instr i stages LDS rows i*32 + wave*8 + (l>>3), chunk l&7
  int gswz = (lane & 7) ^ (lane >> 3);
  int rof = mb * BM + wave * 8 + (lane >> 3);
  const char* xsrc = (const char*)xbf;

  // fs map: fi = tid + i*256 -> row n=fi>>4 in [0,48), float4 chunk c=fi&15
  int fn[3], fc[3];
  #pragma unroll
  for (int i = 0; i < 3; i++) { int fi = tid + i * 256; fn[i] = fi >> 4; fc[i] = fi & 15; }

  f32x4 acc[2][3];
  #pragma unroll
  for (int i = 0; i < 2; i++)
    #pragma unroll
    for (int j = 0; j < 3; j++) acc[i][j] = f32x4{0.f, 0.f, 0.f, 0.f};

  for (int t = 0; t < NK; t++) {
    int k0 = t * KC;
    __syncthreads();   // xs/fs reusable (prev compute done)
    // ---- stage ----
    float4 fv[3];
    #pragma unroll
    for (int i = 0; i < 3; i++)
      fv[i] = *(const float4*)(feats + (size_t)(n0 + fn[i]) * D_ + k0 + 4 * fc[i]);
    size_t gb = ((size_t)rof * D_ + k0 + gswz * 8) * 2;
    #pragma unroll
    for (int i = 0; i < 4; i++)
      GLOAD16(xsrc + gb + (size_t)i * 32 * D_ * 2,
              (char*)xs + i * 4096 + wave * 1024);
    #pragma unroll
    for (int i = 0; i < 3; i++) {
      union { __hip_bfloat162 h2[2]; uint2 u8; } pk;
      pk.h2[0] = __float22bfloat162_rn(make_float2(fv[i].x, fv[i].y));
      pk.h2[1] = __float22bfloat162_rn(make_float2(fv[i].z, fv[i].w));
      int byte = fn[i] * 128 + ((8 * fc[i]) ^ ((fn[i] & 7) << 4));
      *(uint2*)((char*)fs + byte) = pk.u8;
    }
    __syncthreads();   // drain loads: xs (gl_lds) + fs visible
    // ---- compute ----
    #pragma unroll
    for (int ks = 0; ks < 2; ks++) {
      int g = ks * 4 + q;
      bf16x8 a[2], bb[3];
      #pragma unroll
      for (int mi = 0; mi < 2; mi++) {
        int row = wave * 32 + mi * 16 + lr;
        a[mi] = *(const bf16x8*)((char*)xs + row * 128 + ((g * 16) ^ ((row & 7) << 4)));
      }
      #pragma unroll
      for (int ni = 0; ni < 3; ni++) {
        int row = ni * 16 + lr;
        bb[ni] = *(const bf16x8*)((char*)fs + row * 128 + ((g * 16) ^ ((row & 7) << 4)));
      }
      #pragma unroll
      for (int mi = 0; mi < 2; mi++)
        #pragma unroll
        for (int ni = 0; ni < 3; ni++)
          acc[mi][ni] = __builtin_amdgcn_mfma_f32_16x16x32_bf16(a[mi], bb[ni], acc[mi][ni], 0, 0, 0);
    }
  }

  // ---- epilogue: per-row partial max/sumexp over this block's 48 cols ----
  #pragma unroll
  for (int mi = 0; mi < 2; mi++) {
    #pragma unroll
    for (int r = 0; r < 4; r++) {
      float v0 = acc[mi][0][r] * INV_TEMP;
      float v1 = acc[mi][1][r] * INV_TEMP;
      float v2 = acc[mi][2][r] * INV_TEMP;
      float mx = fmaxf(fmaxf(v0, v1), v2);
      #pragma unroll
      for (int m = 8; m >= 1; m >>= 1) mx = fmaxf(mx, __shfl_xor(mx, m, 64));
      float s = __expf(v0 - mx) + __expf(v1 - mx) + __expf(v2 - mx);
      #pragma unroll
      for (int m = 8; m >= 1; m >>= 1) s += __shfl_xor(s, m, 64);
      if (lr == 0) {
        int row = mb * BM + wave * 32 + mi * 16 + q * 4 + r;
        pmax[(size_t)nb * 256 + row] = mx;
        psum[(size_t)nb * 256 + row] = s;
      }
    }
  }
}

// ---------------- Kernel B2: streaming copy feats -> out+1 ------------------
// Carry-shuffle: every store is an aligned float4 fully covering its sectors.
__global__ __launch_bounds__(256) void kcopy(const float* __restrict__ feats,
                                             float* __restrict__ outp) {
  const size_t NF4 = (size_t)N_ * D_ / 4;  // 15,360,000
  size_t stride = (size_t)gridDim.x * 256;
  int lane = threadIdx.x & 63;
  int slp = (lane - 1) & 63;
  for (size_t idx = (size_t)blockIdx.x * 256 + threadIdx.x; idx < NF4; idx += stride) {
    float4 v = *(const float4*)(feats + 4 * idx);
    float pw = __shfl(v.w, slp, 64);
    float prev = (lane == 0) ? ((idx == 0) ? 0.f : feats[4 * idx - 1]) : pw;
    if (idx == 0) { outp[1] = v.x; outp[2] = v.y; outp[3] = v.z; }
    else *(float4*)(outp + 4 * idx) = make_float4(prev, v.x, v.y, v.z);
    if (idx == NF4 - 1) outp[4 * idx + 4] = v.w;
  }
}

// ---------------- Kernel C: exact fp32 target logits ------------------------
__global__ __launch_bounds__(256) void ktdot(const float* __restrict__ feats,
                                             const float* __restrict__ x,
                                             const int* __restrict__ tgt,
                                             float* __restrict__ tdot) {
  int b = blockIdx.x, t = threadIdx.x;
  int y = tgt[b];
  const float* fr = feats + (size_t)y * D_;
  const float* xr = x + (size_t)b * D_;
  float s = 0.f;
  #pragma unroll
  for (int i = 0; i < 8; i++) s += fr[t + i * 256] * xr[t + i * 256];
  float tot = blockReduceSum256(s);
  if (t == 0) tdot[b] = tot * INV_TEMP;
}

// ---------------- Kernel D1: coalesced tile-range combine (40 blocks) -------
__global__ __launch_bounds__(256) void kloss1(const float* __restrict__ pmax,
                                              const float* __restrict__ psum,
                                              float* __restrict__ pm2,
                                              float* __restrict__ ps2) {
  int b = threadIdx.x, j = blockIdx.x;
  float m = -INFINITY, s = 0.f;
  #pragma unroll 4
  for (int i = 0; i < TPB; i++) {
    int tile = j * TPB + i;
    if (tile >= NT) break;
    float mt = pmax[(size_t)tile * 256 + b];
    float st = psum[(size_t)tile * 256 + b];
    if (mt > m) { s = s * __expf(m - mt) + st; m = mt; }
    else        { s += st * __expf(mt - m); }
  }
  pm2[j * 256 + b] = m;
  ps2[j * 256 + b] = s;
}

// ---------------- Kernel D2: final combine + mean -> loss -------------------
__global__ __launch_bounds__(256) void kloss2(const float* __restrict__ pm2,
                                              const float* __restrict__ ps2,
                                              const float* __restrict__ tdot,
                                              float* __restrict__ out) {
  int b = threadIdx.x;
  float m = -INFINITY, s = 0.f;
  for (int j = 0; j < NBL; j++) {
    float mt = pm2[j * 256 + b];
    float st = ps2[j * 256 + b];
    float M = fmaxf(m, mt);
    s = s * __expf(m - M) + st * __expf(mt - M);
    m = M;
  }
  float lb = m + logf(s) - tdot[b];
  float tot = blockReduceSum256(lb);
  if (b == 0) out[0] = tot * (1.0f / 256.0f);
}

// ---------------- Kernel E: momentum update (first-occurrence chains) -------
__global__ __launch_bounds__(256) void kupdate(const float* __restrict__ feats,
                                               const float* __restrict__ x,
                                               const int* __restrict__ tgt,
                                               float* __restrict__ outF) {
  int b = blockIdx.x, t = threadIdx.x;
  int y = tgt[b];
  for (int i = 0; i < b; i++) if (tgt[i] == y) return;  // block-uniform exit
  float f[8];
  #pragma unroll
  for (int i = 0; i < 8; i++) f[i] = feats[(size_t)y * D_ + t + i * 256];
  for (int b2 = b; b2 < B_; b2++) {
    if (tgt[b2] != y) continue;  // block-uniform
    float ss = 0.f;
    #pragma unroll
    for (int i = 0; i < 8; i++) {
      f[i] = MOM * f[i] + (1.0f - MOM) * x[(size_t)b2 * D_ + t + i * 256];
      ss += f[i] * f[i];
    }
    float tot = blockReduceSum256(ss);
    float inv = 1.0f / (sqrtf(tot) + EPSF);
    #pragma unroll
    for (int i = 0; i < 8; i++) f[i] *= inv;
  }
  #pragma unroll
  for (int i = 0; i < 8; i++) outF[(size_t)y * D_ + t + i * 256] = f[i];
}

extern "C" void kernel_launch(void* const* d_in, const int* in_sizes, int n_in,
                              void* d_out, int out_size, void* d_ws, size_t ws_size,
                              hipStream_t stream) {
  const float* inputs = (const float*)d_in[0];
  const float* feats  = (const float*)d_in[1];
  const int*   tgt    = (const int*)d_in[2];
  float* out  = (float*)d_out;
  float* outF = out + 1;  // new_features, N_ x D_

  char* ws = (char*)d_ws;
  size_t off = 0;
  float*          x    = (float*)(ws + off);            off += (size_t)B_ * D_ * 4;
  unsigned short* xbf  = (unsigned short*)(ws + off);   off += (size_t)B_ * D_ * 2;
  float*          pmax = (float*)(ws + off);            off += (size_t)NT * 256 * 4;
  float*          psum = (float*)(ws + off);            off += (size_t)NT * 256 * 4;
  float*          pm2  = (float*)(ws + off);            off += (size_t)NBL * 256 * 4;
  float*          ps2  = (float*)(ws + off);            off += (size_t)NBL * 256 * 4;
  float*          tdot = (float*)(ws + off);

  hipLaunchKernelGGL(knorm,   dim3(B_),    dim3(256), 0, stream, inputs, x, xbf);
  hipLaunchKernelGGL(kmain,   dim3(1250),  dim3(256), 0, stream, feats, xbf, pmax, psum);
  hipLaunchKernelGGL(ktdot,   dim3(B_),    dim3(256), 0, stream, feats, x, tgt, tdot);
  hipLaunchKernelGGL(kloss1,  dim3(NBL),   dim3(256), 0, stream, pmax, psum, pm2, ps2);
  hipLaunchKernelGGL(kloss2,  dim3(1),     dim3(256), 0, stream, pm2, ps2, tdot, out);
  hipLaunchKernelGGL(kcopy,   dim3(2048),  dim3(256), 0, stream, feats, out);
  hipLaunchKernelGGL(kupdate, dim3(B_),    dim3(256), 0, stream, feats, x, tgt, outF);
}